// Round 6
// baseline (245.137 us; speedup 1.0000x reference)
//
#include <hip/hip_runtime.h>
#include <math.h>

#define T_STEPS 256
#define BS      512
#define N       2048
#define WAVE    64
#define EPT     (N / WAVE)    // 32 elements per thread
#define FUDGE   1e-4f

// Keep coefficient values opaque so the compiler cannot re-load them from
// global memory inside the scan loop.
#define PIN8(A, B) asm volatile("" \
    : "+v"((A)[(B)+0]), "+v"((A)[(B)+1]), "+v"((A)[(B)+2]), "+v"((A)[(B)+3]), \
      "+v"((A)[(B)+4]), "+v"((A)[(B)+5]), "+v"((A)[(B)+6]), "+v"((A)[(B)+7]))
#define PIN32(A) do { PIN8(A,0); PIN8(A,8); PIN8(A,16); PIN8(A,24); } while (0)

// --- wave64 all-lanes sum via DPP ---------------------------------------
template <int CTRL>
__device__ __forceinline__ float dpp_add(float v) {
    int sh = __builtin_amdgcn_update_dpp(0, __float_as_int(v), CTRL, 0xf, 0xf, true);
    return v + __int_as_float(sh);
}

__device__ __forceinline__ float wave_allsum(float v) {
    v = dpp_add<0x111>(v);  // row_shr:1
    v = dpp_add<0x112>(v);  // row_shr:2
    v = dpp_add<0x114>(v);  // row_shr:4
    v = dpp_add<0x118>(v);  // row_shr:8
    v = dpp_add<0x142>(v);  // row_bcast:15
    v = dpp_add<0x143>(v);  // row_bcast:31
    return __int_as_float(__builtin_amdgcn_readlane(__float_as_int(v), 63));
}

// One wave per batch element; no barriers in the scan loop; all state in
// registers. amdgpu_waves_per_eu(1,1): the grid only supplies 2 waves/CU,
// so tell regalloc to use the full 512-VGPR/wave budget instead of its
// default ~5-waves/EU heuristic (which capped us at 96 VGPRs and spilled
// the coefficient arrays to L1-backed scratch -> ~1100 stall cy/step).
__global__ __attribute__((amdgpu_waves_per_eu(1, 1))) __launch_bounds__(WAVE)
void legacy_elbo_scan_kernel(
    const float* __restrict__ noises,   // [T, BS]
    const float* __restrict__ ys,       // [T]
    const float* __restrict__ qs,       // [T]
    const float* __restrict__ z_biases, // [N]
    const float* __restrict__ w_in,     // [N]
    const float* __restrict__ w_inq,    // [N]
    const float* __restrict__ p_llr,
    const float* __restrict__ p_llrd,
    const float* __restrict__ p_sigb,
    const float* __restrict__ p_oscale,
    const float* __restrict__ p_ufs,
    const float* __restrict__ p_lwd,
    const float* __restrict__ p_qscale,
    const float* __restrict__ p_tauq,
    const float* __restrict__ p_tauy,
    float* __restrict__ out)            // [T, BS]
{
    const int lane = threadIdx.x;       // 0..63
    const int blk  = blockIdx.x;        // batch index k

    __shared__ float ys_s[T_STEPS];
    __shared__ float qs_s[T_STEPS];
    __shared__ float nz_s[T_STEPS];

#pragma unroll
    for (int i = 0; i < T_STEPS / WAVE; ++i) {
        const int t = lane + (i << 6);
        ys_s[t] = ys[t];
        qs_s[t] = qs[t];
        nz_s[t] = noises[t * BS + blk];
    }

    const float llr     = p_llr[0];
    const float llrd    = p_llrd[0];
    const float sigb    = p_sigb[0];
    const float oscale  = p_oscale[0];
    const float ufs     = p_ufs[0];
    const float lwd     = p_lwd[0];
    const float qscale  = p_qscale[0];
    const float tauq_m1 = p_tauq[0];
    const float tauy_m1 = p_tauy[0];

    const float lr0      = expf(llr);
    const float lr_decay = expf(llrd);
    const float wd       = expf(lwd);
    const float rwd      = 1.0f / wd;
    const float tauq     = 1.0f + log1pf(expf(tauq_m1));
    const float tauy     = 1.0f + log1pf(expf(tauy_m1));
    const float omtq     = 1.0f - tauq;
    const float omty     = 1.0f - tauy;

    // Persistent per-thread state: 32 feature lanes each, coalesced loads.
    float v[EPT], bias[EPT], win[EPT], winq[EPT];
#pragma unroll
    for (int i = 0; i < EPT; ++i) {
        const int j = lane + i * WAVE;
        bias[i] = sigb * z_biases[j];
        win[i]  = w_in[j];
        winq[i] = w_inq[j];
        v[i]    = 0.0f;
    }
    // Pin coefficients into VGPRs.
    PIN32(bias); PIN32(win); PIN32(winq);

    float u = 0.0f, e = 0.0f, lr_mult = 1.0f, qlp = 0.0f, ylp = 0.0f;
    float sp = 1.0f, rsp = 1.0f;        // wd^t and 1/wd^t

    __syncthreads();                    // drain staging (single wave)

    float q_c = qs_s[0], y_c = ys_s[0], n_c = nz_s[0];

    for (int t = 0; t < T_STEPS; ++t) {
        const int tn = (t + 1 < T_STEPS) ? t + 1 : t;
        const float q_n = qs_s[tn], y_n = ys_s[tn], n_n = nz_s[tn];

        qlp = omtq * qlp + tauq * q_c;
        const float qsc = qscale * qlp;
        const float x   = fmaf(u, ufs, e) + n_c;

        float su[4] = {0.f, 0.f, 0.f, 0.f};
        float sh[4] = {0.f, 0.f, 0.f, 0.f};
        float h[EPT];
#pragma unroll
        for (int i = 0; i < EPT; ++i) {
            float hv = fmaf(x, win[i], fmaf(winq[i], qsc, bias[i]));
            hv = fmaxf(hv, 0.0f);
            h[i] = hv;
            su[i & 3] = fmaf(v[i], hv, su[i & 3]);
            sh[i & 3] = fmaf(hv, hv, sh[i & 3]);
        }
        const float su_t = wave_allsum((su[0] + su[1]) + (su[2] + su[3]));
        const float sh2  = wave_allsum((sh[0] + sh[1]) + (sh[2] + sh[3]));

        u = sp * su_t;                  // w_t = sp * v_t
        if (lane == 0) out[t * BS + blk] = oscale * u;

        ylp = omty * ylp + tauy * y_c;
        e = ylp - u;
        const float el = e * (lr0 * lr_mult);
        const float c  = el * rsp;      // dw coefficient in v-space

#pragma unroll
        for (int i = 0; i < EPT; ++i)
            v[i] = fmaf(c, h[i], v[i]);

        const float nrm = sqrtf(fmaf(el * el, sh2, FUDGE));
        lr_mult *= expf(-lr_decay * nrm);
        sp  *= wd;
        rsp *= rwd;

        q_c = q_n; y_c = y_n; n_c = n_n;
    }
}

extern "C" void kernel_launch(void* const* d_in, const int* in_sizes, int n_in,
                              void* d_out, int out_size, void* d_ws, size_t ws_size,
                              hipStream_t stream) {
    (void)in_sizes; (void)n_in; (void)d_ws; (void)ws_size; (void)out_size;
    const float* noises   = (const float*)d_in[0];
    const float* ys       = (const float*)d_in[1];
    const float* qs       = (const float*)d_in[2];
    const float* z_biases = (const float*)d_in[3];
    const float* w_in     = (const float*)d_in[4];
    const float* w_inq    = (const float*)d_in[5];
    const float* llr      = (const float*)d_in[6];
    const float* llrd     = (const float*)d_in[7];
    const float* sigb     = (const float*)d_in[8];
    const float* oscale   = (const float*)d_in[9];
    const float* ufs      = (const float*)d_in[10];
    const float* lwd      = (const float*)d_in[11];
    const float* qscale   = (const float*)d_in[12];
    const float* tauq     = (const float*)d_in[13];
    const float* tauy     = (const float*)d_in[14];
    float* out = (float*)d_out;

    hipLaunchKernelGGL(legacy_elbo_scan_kernel, dim3(BS), dim3(WAVE), 0, stream,
                       noises, ys, qs, z_biases, w_in, w_inq,
                       llr, llrd, sigb, oscale, ufs, lwd, qscale, tauq, tauy,
                       out);
}

// Round 7
// 218.759 us; speedup vs baseline: 1.1206x; 1.1206x over previous
//
#include <hip/hip_runtime.h>
#include <math.h>

#define T_STEPS 256
#define BS      512
#define N       2048
#define WAVE    64
#define EPT     (N / WAVE)    // 32 elements per thread
#define NCHUNK  (EPT / 4)     // 8 float4 chunks per thread
#define FUDGE   1e-4f

// --- wave64 all-lanes sum via DPP ---------------------------------------
template <int CTRL>
__device__ __forceinline__ float dpp_add(float v) {
    int sh = __builtin_amdgcn_update_dpp(0, __float_as_int(v), CTRL, 0xf, 0xf, true);
    return v + __int_as_float(sh);
}

__device__ __forceinline__ float wave_allsum(float v) {
    v = dpp_add<0x111>(v);  // row_shr:1
    v = dpp_add<0x112>(v);  // row_shr:2
    v = dpp_add<0x114>(v);  // row_shr:4
    v = dpp_add<0x118>(v);  // row_shr:8
    v = dpp_add<0x142>(v);  // row_bcast:15
    v = dpp_add<0x143>(v);  // row_bcast:31
    return __int_as_float(__builtin_amdgcn_readlane(__float_as_int(v), 63));
}

// One wave per batch element; no barriers in the scan loop.
// R3-R6 lesson: regalloc refuses to keep the 96 coefficient floats resident
// (VGPR=96/132 observed, per-step L1 reloads, ~1100 exposed cy/step). So the
// coefficients live in LDS instead: 24 ds_read_b128 per step, short-latency,
// deeply pipelined under the h-loop math. Register live set is just
// v[32]+h[32]+temps, which the allocator keeps without a fight.
// w_out kept scaled: w_t = sp_t * v_t, sp_t = wd^t => update is a single fma;
// norms = sqrt(FUDGE + (e*lr)^2 * sum h^2) (algebraically = reference).
__global__ __attribute__((amdgpu_waves_per_eu(1, 1))) __launch_bounds__(WAVE)
void legacy_elbo_scan_kernel(
    const float* __restrict__ noises,   // [T, BS]
    const float* __restrict__ ys,       // [T]
    const float* __restrict__ qs,       // [T]
    const float* __restrict__ z_biases, // [N]
    const float* __restrict__ w_in,     // [N]
    const float* __restrict__ w_inq,    // [N]
    const float* __restrict__ p_llr,
    const float* __restrict__ p_llrd,
    const float* __restrict__ p_sigb,
    const float* __restrict__ p_oscale,
    const float* __restrict__ p_ufs,
    const float* __restrict__ p_lwd,
    const float* __restrict__ p_qscale,
    const float* __restrict__ p_tauq,
    const float* __restrict__ p_tauy,
    float* __restrict__ out)            // [T, BS]
{
    const int lane = threadIdx.x;       // 0..63
    const int blk  = blockIdx.x;        // batch index k

    __shared__ float4 cb[N / 4];        // sigb * z_biases
    __shared__ float4 cw[N / 4];        // w_in
    __shared__ float4 cq[N / 4];        // w_inq
    __shared__ float  ys_s[T_STEPS];
    __shared__ float  qs_s[T_STEPS];
    __shared__ float  nz_s[T_STEPS];

    const float sigb = p_sigb[0];

    // Stage coefficients into LDS (float4, coalesced 16B/lane).
    const float4* zb4 = (const float4*)z_biases;
    const float4* wi4 = (const float4*)w_in;
    const float4* wq4 = (const float4*)w_inq;
#pragma unroll
    for (int i = 0; i < NCHUNK; ++i) {
        const int idx = lane + (i << 6);       // 0..511
        float4 b = zb4[idx];
        b.x *= sigb; b.y *= sigb; b.z *= sigb; b.w *= sigb;
        cb[idx] = b;
        cw[idx] = wi4[idx];
        cq[idx] = wq4[idx];
    }
#pragma unroll
    for (int i = 0; i < T_STEPS / WAVE; ++i) {
        const int t = lane + (i << 6);
        ys_s[t] = ys[t];
        qs_s[t] = qs[t];
        nz_s[t] = noises[t * BS + blk];
    }

    const float llr     = p_llr[0];
    const float llrd    = p_llrd[0];
    const float oscale  = p_oscale[0];
    const float ufs     = p_ufs[0];
    const float lwd     = p_lwd[0];
    const float qscale  = p_qscale[0];
    const float tauq_m1 = p_tauq[0];
    const float tauy_m1 = p_tauy[0];

    const float lr0      = expf(llr);
    const float lr_decay = expf(llrd);
    const float wd       = expf(lwd);
    const float rwd      = 1.0f / wd;
    const float tauq     = 1.0f + log1pf(expf(tauq_m1));
    const float tauy     = 1.0f + log1pf(expf(tauy_m1));
    const float omtq     = 1.0f - tauq;
    const float omty     = 1.0f - tauy;

    // Persistent per-thread state: just the output weights (v-space).
    float v[EPT];
#pragma unroll
    for (int i = 0; i < EPT; ++i) v[i] = 0.0f;

    float u = 0.0f, e = 0.0f, lr_mult = 1.0f, qlp = 0.0f, ylp = 0.0f;
    float sp = 1.0f, rsp = 1.0f;        // wd^t and 1/wd^t

    __syncthreads();                    // drain staging (single wave)

    float q_c = qs_s[0], y_c = ys_s[0], n_c = nz_s[0];

    for (int t = 0; t < T_STEPS; ++t) {
        const int tn = (t + 1 < T_STEPS) ? t + 1 : t;
        const float q_n = qs_s[tn], y_n = ys_s[tn], n_n = nz_s[tn];

        qlp = omtq * qlp + tauq * q_c;
        const float qsc = qscale * qlp;
        const float x   = fmaf(u, ufs, e) + n_c;

        float su0 = 0.f, su1 = 0.f, sh0 = 0.f, sh1 = 0.f;
        float h[EPT];
#pragma unroll
        for (int c = 0; c < NCHUNK; ++c) {
            const int idx = lane + (c << 6);
            const float4 b4 = cb[idx];
            const float4 w4 = cw[idx];
            const float4 g4 = cq[idx];
            float h0 = fmaxf(fmaf(x, w4.x, fmaf(qsc, g4.x, b4.x)), 0.0f);
            float h1 = fmaxf(fmaf(x, w4.y, fmaf(qsc, g4.y, b4.y)), 0.0f);
            float h2 = fmaxf(fmaf(x, w4.z, fmaf(qsc, g4.z, b4.z)), 0.0f);
            float h3 = fmaxf(fmaf(x, w4.w, fmaf(qsc, g4.w, b4.w)), 0.0f);
            h[4*c+0] = h0; h[4*c+1] = h1; h[4*c+2] = h2; h[4*c+3] = h3;
            su0 = fmaf(v[4*c+0], h0, su0);
            su1 = fmaf(v[4*c+1], h1, su1);
            su0 = fmaf(v[4*c+2], h2, su0);
            su1 = fmaf(v[4*c+3], h3, su1);
            sh0 = fmaf(h0, h0, sh0);
            sh1 = fmaf(h1, h1, sh1);
            sh0 = fmaf(h2, h2, sh0);
            sh1 = fmaf(h3, h3, sh1);
        }
        const float su_t = wave_allsum(su0 + su1);
        const float sh2  = wave_allsum(sh0 + sh1);

        u = sp * su_t;                  // w_t = sp * v_t
        if (lane == 0) out[t * BS + blk] = oscale * u;

        ylp = omty * ylp + tauy * y_c;
        e = ylp - u;
        const float el = e * (lr0 * lr_mult);
        const float c  = el * rsp;      // dw coefficient in v-space

#pragma unroll
        for (int i = 0; i < EPT; ++i)
            v[i] = fmaf(c, h[i], v[i]);

        const float nrm = sqrtf(fmaf(el * el, sh2, FUDGE));
        lr_mult *= expf(-lr_decay * nrm);
        sp  *= wd;
        rsp *= rwd;

        q_c = q_n; y_c = y_n; n_c = n_n;
    }
}

extern "C" void kernel_launch(void* const* d_in, const int* in_sizes, int n_in,
                              void* d_out, int out_size, void* d_ws, size_t ws_size,
                              hipStream_t stream) {
    (void)in_sizes; (void)n_in; (void)d_ws; (void)ws_size; (void)out_size;
    const float* noises   = (const float*)d_in[0];
    const float* ys       = (const float*)d_in[1];
    const float* qs       = (const float*)d_in[2];
    const float* z_biases = (const float*)d_in[3];
    const float* w_in     = (const float*)d_in[4];
    const float* w_inq    = (const float*)d_in[5];
    const float* llr      = (const float*)d_in[6];
    const float* llrd     = (const float*)d_in[7];
    const float* sigb     = (const float*)d_in[8];
    const float* oscale   = (const float*)d_in[9];
    const float* ufs      = (const float*)d_in[10];
    const float* lwd      = (const float*)d_in[11];
    const float* qscale   = (const float*)d_in[12];
    const float* tauq     = (const float*)d_in[13];
    const float* tauy     = (const float*)d_in[14];
    float* out = (float*)d_out;

    hipLaunchKernelGGL(legacy_elbo_scan_kernel, dim3(BS), dim3(WAVE), 0, stream,
                       noises, ys, qs, z_biases, w_in, w_inq,
                       llr, llrd, sigb, oscale, ufs, lwd, qscale, tauq, tauy,
                       out);
}

// Round 8
// 213.223 us; speedup vs baseline: 1.1497x; 1.0260x over previous
//
#include <hip/hip_runtime.h>
#include <math.h>

#define T_STEPS 256
#define BS      512
#define N       2048
#define BLOCK   256               // 4 waves per batch element -> 2 waves/SIMD
#define NWAVE   (BLOCK / 64)      // 4
#define EPT     (N / BLOCK)       // 8 elements per thread
#define NCHUNK  (EPT / 4)         // 2 float4 chunks per thread
#define FUDGE   1e-4f

// --- wave64 sum via DPP: lane 63 holds the wave total --------------------
template <int CTRL>
__device__ __forceinline__ float dpp_add(float v) {
    int sh = __builtin_amdgcn_update_dpp(0, __float_as_int(v), CTRL, 0xf, 0xf, true);
    return v + __int_as_float(sh);
}

__device__ __forceinline__ float wave_sum_lane63(float v) {
    v = dpp_add<0x111>(v);  // row_shr:1
    v = dpp_add<0x112>(v);  // row_shr:2
    v = dpp_add<0x114>(v);  // row_shr:4
    v = dpp_add<0x118>(v);  // row_shr:8
    v = dpp_add<0x142>(v);  // row_bcast:15
    v = dpp_add<0x143>(v);  // row_bcast:31
    return v;               // total valid in lane 63
}

// One 4-wave block per batch element; coefficients in LDS (R7 fix: regalloc
// refuses to keep them in VGPRs and reloads from L1 every step); 4-wave
// split gives 2 waves/SIMD so stalls of one block hide under the other.
// Per step: fused in-wave DPP reduce of (sum w*h, sum h^2), 4-wave combine
// via parity double-buffered LDS, ONE __syncthreads per step.
// w_out kept scaled: w_t = sp_t * v_t, sp_t = wd^t => update is one fma;
// norms = sqrt(FUDGE + (e*lr)^2 * sum h^2) (algebraically = reference).
__global__ __launch_bounds__(BLOCK)
void legacy_elbo_scan_kernel(
    const float* __restrict__ noises,   // [T, BS]
    const float* __restrict__ ys,       // [T]
    const float* __restrict__ qs,       // [T]
    const float* __restrict__ z_biases, // [N]
    const float* __restrict__ w_in,     // [N]
    const float* __restrict__ w_inq,    // [N]
    const float* __restrict__ p_llr,
    const float* __restrict__ p_llrd,
    const float* __restrict__ p_sigb,
    const float* __restrict__ p_oscale,
    const float* __restrict__ p_ufs,
    const float* __restrict__ p_lwd,
    const float* __restrict__ p_qscale,
    const float* __restrict__ p_tauq,
    const float* __restrict__ p_tauy,
    float* __restrict__ out)            // [T, BS]
{
    const int tid  = threadIdx.x;
    const int lane = tid & 63;
    const int wid  = tid >> 6;          // 0..3
    const int blk  = blockIdx.x;        // batch index k

    __shared__ float4 cb[N / 4];        // sigb * z_biases
    __shared__ float4 cw[N / 4];        // w_in
    __shared__ float4 cq[N / 4];        // w_inq
    __shared__ float  ys_s[T_STEPS];
    __shared__ float  qs_s[T_STEPS];
    __shared__ float  nz_s[T_STEPS];
    __shared__ float  red[2][2 * NWAVE];  // [parity][wave*2 + {su,sh2}]

    const float sigb = p_sigb[0];

    // Stage coefficients into LDS (float4, coalesced 16B/lane).
    const float4* zb4 = (const float4*)z_biases;
    const float4* wi4 = (const float4*)w_in;
    const float4* wq4 = (const float4*)w_inq;
#pragma unroll
    for (int i = 0; i < NCHUNK; ++i) {
        const int idx = tid + i * BLOCK;       // 0..511
        float4 b = zb4[idx];
        b.x *= sigb; b.y *= sigb; b.z *= sigb; b.w *= sigb;
        cb[idx] = b;
        cw[idx] = wi4[idx];
        cq[idx] = wq4[idx];
    }
    // Per-step scalars: T == BLOCK, one element per thread.
    ys_s[tid] = ys[tid];
    qs_s[tid] = qs[tid];
    nz_s[tid] = noises[tid * BS + blk];

    const float llr     = p_llr[0];
    const float llrd    = p_llrd[0];
    const float oscale  = p_oscale[0];
    const float ufs     = p_ufs[0];
    const float lwd     = p_lwd[0];
    const float qscale  = p_qscale[0];
    const float tauq_m1 = p_tauq[0];
    const float tauy_m1 = p_tauy[0];

    const float lr0      = expf(llr);
    const float lr_decay = expf(llrd);
    const float wd       = expf(lwd);
    const float rwd      = 1.0f / wd;
    const float tauq     = 1.0f + log1pf(expf(tauq_m1));
    const float tauy     = 1.0f + log1pf(expf(tauy_m1));
    const float omtq     = 1.0f - tauq;
    const float omty     = 1.0f - tauy;

    // Persistent per-thread state: 8 output weights (v-space).
    float v[EPT];
#pragma unroll
    for (int i = 0; i < EPT; ++i) v[i] = 0.0f;

    float u = 0.0f, e = 0.0f, lr_mult = 1.0f, qlp = 0.0f, ylp = 0.0f;
    float sp = 1.0f, rsp = 1.0f;        // wd^t and 1/wd^t

    __syncthreads();

    float q_c = qs_s[0], y_c = ys_s[0], n_c = nz_s[0];

    for (int t = 0; t < T_STEPS; ++t) {
        const int tn = (t + 1 < T_STEPS) ? t + 1 : t;
        const float q_n = qs_s[tn], y_n = ys_s[tn], n_n = nz_s[tn];

        qlp = omtq * qlp + tauq * q_c;
        const float qsc = qscale * qlp;
        const float x   = fmaf(u, ufs, e) + n_c;

        float su0 = 0.f, su1 = 0.f, sh0 = 0.f, sh1 = 0.f;
        float h[EPT];
#pragma unroll
        for (int c = 0; c < NCHUNK; ++c) {
            const int idx = tid + c * BLOCK;
            const float4 b4 = cb[idx];
            const float4 w4 = cw[idx];
            const float4 g4 = cq[idx];
            float h0 = fmaxf(fmaf(x, w4.x, fmaf(qsc, g4.x, b4.x)), 0.0f);
            float h1 = fmaxf(fmaf(x, w4.y, fmaf(qsc, g4.y, b4.y)), 0.0f);
            float h2 = fmaxf(fmaf(x, w4.z, fmaf(qsc, g4.z, b4.z)), 0.0f);
            float h3 = fmaxf(fmaf(x, w4.w, fmaf(qsc, g4.w, b4.w)), 0.0f);
            h[4*c+0] = h0; h[4*c+1] = h1; h[4*c+2] = h2; h[4*c+3] = h3;
            su0 = fmaf(v[4*c+0], h0, su0);
            su1 = fmaf(v[4*c+1], h1, su1);
            su0 = fmaf(v[4*c+2], h2, su0);
            su1 = fmaf(v[4*c+3], h3, su1);
            sh0 = fmaf(h0, h0, sh0);
            sh1 = fmaf(h1, h1, sh1);
            sh0 = fmaf(h2, h2, sh0);
            sh1 = fmaf(h3, h3, sh1);
        }
        float su_w = wave_sum_lane63(su0 + su1);
        float sh_w = wave_sum_lane63(sh0 + sh1);

        const int p = t & 1;
        if (lane == 63) {
            red[p][wid * 2]     = su_w;
            red[p][wid * 2 + 1] = sh_w;
        }
        __syncthreads();                // single barrier per step (parity-safe)
        const float4 r0 = *(const float4*)&red[p][0];
        const float4 r1 = *(const float4*)&red[p][4];
        const float su_t = (r0.x + r0.z) + (r1.x + r1.z);
        const float sh2  = (r0.y + r0.w) + (r1.y + r1.w);

        u = sp * su_t;                  // w_t = sp * v_t
        if (tid == 0) out[t * BS + blk] = oscale * u;

        ylp = omty * ylp + tauy * y_c;
        e = ylp - u;
        const float el = e * (lr0 * lr_mult);
        const float c  = el * rsp;      // dw coefficient in v-space

#pragma unroll
        for (int i = 0; i < EPT; ++i)
            v[i] = fmaf(c, h[i], v[i]);

        const float nrm = sqrtf(fmaf(el * el, sh2, FUDGE));
        lr_mult *= expf(-lr_decay * nrm);
        sp  *= wd;
        rsp *= rwd;

        q_c = q_n; y_c = y_n; n_c = n_n;
    }
}

extern "C" void kernel_launch(void* const* d_in, const int* in_sizes, int n_in,
                              void* d_out, int out_size, void* d_ws, size_t ws_size,
                              hipStream_t stream) {
    (void)in_sizes; (void)n_in; (void)d_ws; (void)ws_size; (void)out_size;
    const float* noises   = (const float*)d_in[0];
    const float* ys       = (const float*)d_in[1];
    const float* qs       = (const float*)d_in[2];
    const float* z_biases = (const float*)d_in[3];
    const float* w_in     = (const float*)d_in[4];
    const float* w_inq    = (const float*)d_in[5];
    const float* llr      = (const float*)d_in[6];
    const float* llrd     = (const float*)d_in[7];
    const float* sigb     = (const float*)d_in[8];
    const float* oscale   = (const float*)d_in[9];
    const float* ufs      = (const float*)d_in[10];
    const float* lwd      = (const float*)d_in[11];
    const float* qscale   = (const float*)d_in[12];
    const float* tauq     = (const float*)d_in[13];
    const float* tauy     = (const float*)d_in[14];
    float* out = (float*)d_out;

    hipLaunchKernelGGL(legacy_elbo_scan_kernel, dim3(BS), dim3(BLOCK), 0, stream,
                       noises, ys, qs, z_biases, w_in, w_inq,
                       llr, llrd, sigb, oscale, ufs, lwd, qscale, tauq, tauy,
                       out);
}

// Round 9
// 196.157 us; speedup vs baseline: 1.2497x; 1.0870x over previous
//
#include <hip/hip_runtime.h>
#include <math.h>

#define T_STEPS 256
#define BS      512
#define N       2048
#define BLOCK   256               // 4 waves per batch element -> 2 waves/SIMD
#define NWAVE   (BLOCK / 64)      // 4
#define EPT     (N / BLOCK)       // 8 elements per thread
#define NCHUNK  (EPT / 4)         // 2 float4 chunks per thread
#define FUDGE   1e-4f

// --- wave64 sum via DPP: lane 63 holds the wave total --------------------
template <int CTRL>
__device__ __forceinline__ float dpp_add(float v) {
    int sh = __builtin_amdgcn_update_dpp(0, __float_as_int(v), CTRL, 0xf, 0xf, true);
    return v + __int_as_float(sh);
}

__device__ __forceinline__ float wave_sum_lane63(float v) {
    v = dpp_add<0x111>(v);  // row_shr:1
    v = dpp_add<0x112>(v);  // row_shr:2
    v = dpp_add<0x114>(v);  // row_shr:4
    v = dpp_add<0x118>(v);  // row_shr:8
    v = dpp_add<0x142>(v);  // row_bcast:15
    v = dpp_add<0x143>(v);  // row_bcast:31
    return v;               // total valid in lane 63
}

// R8 lesson: 4-wave split fixed latency hiding (VALUBusy 33->72%) but wall
// stayed at ~1390 cy/step -- now VALU-issue-bound. This round cuts issue:
// at EPT=8 the coefficients are only 24 floats/lane, and with
// __launch_bounds__(256,2) the register budget is 256 VGPRs (we really run
// 2 waves/EU), so they stay resident -- no per-step LDS reads, no address
// math, no remat pressure (the R1/R3 remat was caused by the default
// 8-waves/EU 64-VGPR budget). __expf replaces libm expf in the loop.
__global__ __launch_bounds__(BLOCK, 2)
void legacy_elbo_scan_kernel(
    const float* __restrict__ noises,   // [T, BS]
    const float* __restrict__ ys,       // [T]
    const float* __restrict__ qs,       // [T]
    const float* __restrict__ z_biases, // [N]
    const float* __restrict__ w_in,     // [N]
    const float* __restrict__ w_inq,    // [N]
    const float* __restrict__ p_llr,
    const float* __restrict__ p_llrd,
    const float* __restrict__ p_sigb,
    const float* __restrict__ p_oscale,
    const float* __restrict__ p_ufs,
    const float* __restrict__ p_lwd,
    const float* __restrict__ p_qscale,
    const float* __restrict__ p_tauq,
    const float* __restrict__ p_tauy,
    float* __restrict__ out)            // [T, BS]
{
    const int tid  = threadIdx.x;
    const int lane = tid & 63;
    const int wid  = tid >> 6;          // 0..3
    const int blk  = blockIdx.x;        // batch index k

    __shared__ float ys_s[T_STEPS];
    __shared__ float qs_s[T_STEPS];
    __shared__ float nz_s[T_STEPS];
    __shared__ float red[2][2 * NWAVE];  // [parity][wave*2 + {su,sh2}]

    const float sigb = p_sigb[0];

    // Per-step scalars: T == BLOCK, one element per thread.
    ys_s[tid] = ys[tid];
    qs_s[tid] = qs[tid];
    nz_s[tid] = noises[tid * BS + blk];

    const float llr     = p_llr[0];
    const float llrd    = p_llrd[0];
    const float oscale  = p_oscale[0];
    const float ufs     = p_ufs[0];
    const float lwd     = p_lwd[0];
    const float qscale  = p_qscale[0];
    const float tauq_m1 = p_tauq[0];
    const float tauy_m1 = p_tauy[0];

    const float lr0      = expf(llr);
    const float lr_decay = expf(llrd);
    const float wd       = expf(lwd);
    const float rwd      = 1.0f / wd;
    const float tauq     = 1.0f + log1pf(expf(tauq_m1));
    const float tauy     = 1.0f + log1pf(expf(tauy_m1));
    const float omtq     = 1.0f - tauq;
    const float omty     = 1.0f - tauy;

    // Coefficients resident in registers: 6 float4 = 24 VGPRs.
    const float4* zb4 = (const float4*)z_biases;
    const float4* wi4 = (const float4*)w_in;
    const float4* wq4 = (const float4*)w_inq;
    float4 cb_r[NCHUNK], cw_r[NCHUNK], cq_r[NCHUNK];
#pragma unroll
    for (int c = 0; c < NCHUNK; ++c) {
        const int idx = tid + c * BLOCK;     // 0..511, coalesced 16B/lane
        float4 b = zb4[idx];
        b.x *= sigb; b.y *= sigb; b.z *= sigb; b.w *= sigb;
        cb_r[c] = b;
        cw_r[c] = wi4[idx];
        cq_r[c] = wq4[idx];
    }

    // Persistent per-thread state: 8 output weights (v-space).
    float v[EPT];
#pragma unroll
    for (int i = 0; i < EPT; ++i) v[i] = 0.0f;

    float u = 0.0f, e = 0.0f, lr_mult = 1.0f, qlp = 0.0f, ylp = 0.0f;
    float sp = 1.0f, rsp = 1.0f;        // wd^t and 1/wd^t

    __syncthreads();

    float q_c = qs_s[0], y_c = ys_s[0], n_c = nz_s[0];

    for (int t = 0; t < T_STEPS; ++t) {
        const int tn = (t + 1 < T_STEPS) ? t + 1 : t;
        const float q_n = qs_s[tn], y_n = ys_s[tn], n_n = nz_s[tn];

        qlp = omtq * qlp + tauq * q_c;
        const float qsc = qscale * qlp;
        const float x   = fmaf(u, ufs, e) + n_c;

        float su0 = 0.f, su1 = 0.f, sh0 = 0.f, sh1 = 0.f;
        float h[EPT];
#pragma unroll
        for (int c = 0; c < NCHUNK; ++c) {
            const float4 b4 = cb_r[c];
            const float4 w4 = cw_r[c];
            const float4 g4 = cq_r[c];
            float h0 = fmaxf(fmaf(x, w4.x, fmaf(qsc, g4.x, b4.x)), 0.0f);
            float h1 = fmaxf(fmaf(x, w4.y, fmaf(qsc, g4.y, b4.y)), 0.0f);
            float h2 = fmaxf(fmaf(x, w4.z, fmaf(qsc, g4.z, b4.z)), 0.0f);
            float h3 = fmaxf(fmaf(x, w4.w, fmaf(qsc, g4.w, b4.w)), 0.0f);
            h[4*c+0] = h0; h[4*c+1] = h1; h[4*c+2] = h2; h[4*c+3] = h3;
            su0 = fmaf(v[4*c+0], h0, su0);
            su1 = fmaf(v[4*c+1], h1, su1);
            su0 = fmaf(v[4*c+2], h2, su0);
            su1 = fmaf(v[4*c+3], h3, su1);
            sh0 = fmaf(h0, h0, sh0);
            sh1 = fmaf(h1, h1, sh1);
            sh0 = fmaf(h2, h2, sh0);
            sh1 = fmaf(h3, h3, sh1);
        }
        float su_w = wave_sum_lane63(su0 + su1);
        float sh_w = wave_sum_lane63(sh0 + sh1);

        const int p = t & 1;
        if (lane == 63) {
            red[p][wid * 2]     = su_w;
            red[p][wid * 2 + 1] = sh_w;
        }
        __syncthreads();                // single barrier per step (parity-safe)
        const float4 r0 = *(const float4*)&red[p][0];
        const float4 r1 = *(const float4*)&red[p][4];
        const float su_t = (r0.x + r0.z) + (r1.x + r1.z);
        const float sh2  = (r0.y + r0.w) + (r1.y + r1.w);

        u = sp * su_t;                  // w_t = sp * v_t
        if (tid == 0) out[t * BS + blk] = oscale * u;

        ylp = omty * ylp + tauy * y_c;
        e = ylp - u;
        const float el = e * (lr0 * lr_mult);
        const float c  = el * rsp;      // dw coefficient in v-space

#pragma unroll
        for (int i = 0; i < EPT; ++i)
            v[i] = fmaf(c, h[i], v[i]);

        const float nrm = sqrtf(fmaf(el * el, sh2, FUDGE));
        lr_mult *= __expf(-lr_decay * nrm);
        sp  *= wd;
        rsp *= rwd;

        q_c = q_n; y_c = y_n; n_c = n_n;
    }
}

extern "C" void kernel_launch(void* const* d_in, const int* in_sizes, int n_in,
                              void* d_out, int out_size, void* d_ws, size_t ws_size,
                              hipStream_t stream) {
    (void)in_sizes; (void)n_in; (void)d_ws; (void)ws_size; (void)out_size;
    const float* noises   = (const float*)d_in[0];
    const float* ys       = (const float*)d_in[1];
    const float* qs       = (const float*)d_in[2];
    const float* z_biases = (const float*)d_in[3];
    const float* w_in     = (const float*)d_in[4];
    const float* w_inq    = (const float*)d_in[5];
    const float* llr      = (const float*)d_in[6];
    const float* llrd     = (const float*)d_in[7];
    const float* sigb     = (const float*)d_in[8];
    const float* oscale   = (const float*)d_in[9];
    const float* ufs      = (const float*)d_in[10];
    const float* lwd      = (const float*)d_in[11];
    const float* qscale   = (const float*)d_in[12];
    const float* tauq     = (const float*)d_in[13];
    const float* tauy     = (const float*)d_in[14];
    float* out = (float*)d_out;

    hipLaunchKernelGGL(legacy_elbo_scan_kernel, dim3(BS), dim3(BLOCK), 0, stream,
                       noises, ys, qs, z_biases, w_in, w_inq,
                       llr, llrd, sigb, oscale, ufs, lwd, qscale, tauq, tauy,
                       out);
}